// Round 1
// baseline (613.898 us; speedup 1.0000x reference)
//
#include <hip/hip_runtime.h>
#include <math.h>

#define NDIM 96
#define NHEADS 6
#define HDIM 16
#define KNB 16
#define FLT_BIG 3.402823466e38f

// ---------------------------------------------------------------- min(xyz)
__global__ void init_min_kernel(float* mn) {
    if (threadIdx.x < 3) mn[threadIdx.x] = FLT_BIG;
}

__global__ void min_reduce_kernel(const float* __restrict__ xyz, int n, float* mn) {
    float m0 = FLT_BIG, m1 = FLT_BIG, m2 = FLT_BIG;
    for (int i = blockIdx.x * blockDim.x + threadIdx.x; i < n; i += gridDim.x * blockDim.x) {
        m0 = fminf(m0, xyz[3 * i + 0]);
        m1 = fminf(m1, xyz[3 * i + 1]);
        m2 = fminf(m2, xyz[3 * i + 2]);
    }
#pragma unroll
    for (int off = 32; off > 0; off >>= 1) {
        m0 = fminf(m0, __shfl_down(m0, off));
        m1 = fminf(m1, __shfl_down(m1, off));
        m2 = fminf(m2, __shfl_down(m2, off));
    }
    if ((threadIdx.x & 63) == 0) {
        // xyz >= 0 so float bit pattern is monotone under signed int compare
        atomicMin((int*)&mn[0], __float_as_int(m0));
        atomicMin((int*)&mn[1], __float_as_int(m1));
        atomicMin((int*)&mn[2], __float_as_int(m2));
    }
}

// ---------------------------------------------------------------- QKV GEMM
// feats (n,96) @ W (96,288) + b -> q*0.25 | k | v, each (n,96)
// grid (9, GY), block 256. Each thread owns one output column j (W column in
// registers), 8 rows per iteration staged in LDS.
__global__ __launch_bounds__(256) void qkv_kernel(
    const float* __restrict__ feats, const float* __restrict__ W,
    const float* __restrict__ b, float* __restrict__ qout,
    float* __restrict__ kout, float* __restrict__ vout, int n) {
    __shared__ float fs[8][96];
    const int t = threadIdx.x;
    const int jj = t & 31;
    const int rl = t >> 5;  // 0..7
    const int j = blockIdx.x * 32 + jj;

    float wreg[96];
#pragma unroll
    for (int d = 0; d < 96; d++) wreg[d] = W[d * 288 + j];
    const float bias = b[j];

    for (int rbase = blockIdx.y * 8; rbase < n; rbase += gridDim.y * 8) {
        __syncthreads();
        for (int idx = t; idx < 768; idx += 256) {
            int rr = idx / 96, dd = idx - rr * 96;
            int r = rbase + rr;
            fs[rr][dd] = (r < n) ? feats[(size_t)r * 96 + dd] : 0.f;
        }
        __syncthreads();
        float acc = bias;
#pragma unroll
        for (int d = 0; d < 96; d++) acc += fs[rl][d] * wreg[d];
        int r = rbase + rl;
        if (r < n) {
            if (j < 96)       qout[(size_t)r * 96 + j]        = acc * 0.25f;
            else if (j < 192) kout[(size_t)r * 96 + (j - 96)] = acc;
            else              vout[(size_t)r * 96 + (j - 192)] = acc;
        }
    }
}

// ---------------------------------------------------------------- table repack
// src layout [idx][h*16+d][c] (stride-3 in d) -> dst [c][idx][h*16+d] contiguous
__global__ void repack_kernel(const float* __restrict__ tq,
                              const float* __restrict__ tk,
                              const float* __restrict__ tv,
                              float* __restrict__ rq, float* __restrict__ rk,
                              float* __restrict__ rv) {
    int i = blockIdx.x * 256 + threadIdx.x;  // over 3*64*96 = 18432
    if (i < 3 * 64 * 96) {
        int c = i / (64 * 96);
        int rem = i - c * 64 * 96;
        int idx = rem / 96;
        int hd = rem - idx * 96;
        int src = (idx * 96 + hd) * 3 + c;
        rq[i] = tq[src];
        rk[i] = tk[src];
        rv[i] = tv[src];
    }
}

// ---------------------------------------------------------------- fused attention
// block = 192 threads = 2 points (96 threads each). Exactly 16 edges/point.
__global__ __launch_bounds__(192) void attn_kernel(
    const float* q, const float* __restrict__ k, const float* __restrict__ v,
    const float* __restrict__ xyz, const int* __restrict__ index_1,
    const float* __restrict__ rq, const float* __restrict__ rk,
    const float* __restrict__ rv, const float* __restrict__ mn,
    const float* __restrict__ shiftp, float* xout, int n) {
    __shared__ float qs[2][96];
    __shared__ float ks[2][16][97];
    __shared__ float vs[2][16][97];
    __shared__ float attn[2][6][16];
    __shared__ int je[2][16];
    __shared__ int ridx[2][16][3];

    const int s = threadIdx.x / 96;
    const int tp = threadIdx.x - s * 96;
    const int p = blockIdx.x * 2 + s;
    const bool active = p < n;

    const float shift = shiftp[0];
    const float mn0 = mn[0], mn1 = mn[1], mn2 = mn[2];

    if (active && tp < 16) {
        const int e = tp;
        const int jdx = index_1[(size_t)p * 16 + e];
        je[s][e] = jdx;
        // xyz_quant for i (p) and j
        float xi0 = floorf(fmodf(xyz[3 * p + 0] - mn0 + shift, 4.0f) * 4.0f);
        float xi1 = floorf(fmodf(xyz[3 * p + 1] - mn1 + shift, 4.0f) * 4.0f);
        float xi2 = floorf(fmodf(xyz[3 * p + 2] - mn2 + shift, 4.0f) * 4.0f);
        float xj0 = floorf(fmodf(xyz[3 * jdx + 0] - mn0 + shift, 4.0f) * 4.0f);
        float xj1 = floorf(fmodf(xyz[3 * jdx + 1] - mn1 + shift, 4.0f) * 4.0f);
        float xj2 = floorf(fmodf(xyz[3 * jdx + 2] - mn2 + shift, 4.0f) * 4.0f);
        ridx[s][e][0] = (int)(xi0 - xj0) + 15;
        ridx[s][e][1] = (int)(xi1 - xj1) + 15;
        ridx[s][e][2] = (int)(xi2 - xj2) + 15;
    }
    __syncthreads();

    if (active) {
        qs[s][tp] = q[(size_t)p * 96 + tp];
#pragma unroll
        for (int e = 0; e < 16; e++) {
            int jdx = je[s][e];
            ks[s][e][tp] = k[(size_t)jdx * 96 + tp];
            vs[s][e][tp] = v[(size_t)jdx * 96 + tp];
        }
    }
    __syncthreads();

    // ---- scores: thread (h,e), h = tp>>4, e = tp&15
    {
        const int h = tp >> 4;
        const int e = tp & 15;
        const float* qrow = &qs[s][h * 16];
        const float* krow = &ks[s][e][h * 16];
        float a = 0.f;
#pragma unroll
        for (int d = 0; d < 16; d++) a += qrow[d] * krow[d];
#pragma unroll
        for (int c = 0; c < 3; c++) {
            int idx = ridx[s][e][c];
            const float* tqp = rq + ((c * 64 + idx) * 96 + h * 16);
            const float* tkp = rk + ((c * 64 + idx) * 96 + h * 16);
#pragma unroll
            for (int d = 0; d < 16; d++) a += qrow[d] * tqp[d] + krow[d] * tkp[d];
        }
        if (active) attn[s][h][e] = a;
    }
    __syncthreads();

    // ---- softmax over e per head (6 threads per point)
    if (active && tp < 6) {
        const int h = tp;
        float m = -FLT_BIG;
#pragma unroll
        for (int e = 0; e < 16; e++) m = fmaxf(m, attn[s][h][e]);
        float ex[16];
        float sum = 0.f;
#pragma unroll
        for (int e = 0; e < 16; e++) {
            ex[e] = expf(attn[s][h][e] - m);
            sum += ex[e];
        }
        float inv = 1.0f / sum;
#pragma unroll
        for (int e = 0; e < 16; e++) attn[s][h][e] = ex[e] * inv;
    }
    __syncthreads();

    // ---- output: thread owns (h,d) = tp, x[tp] = sum_e sm[e,h]*(v + tv)
    {
        const int h = tp >> 4;
        float x = 0.f;
#pragma unroll
        for (int e = 0; e < 16; e++) {
            float w = attn[s][h][e];
            int i0 = ridx[s][e][0], i1 = ridx[s][e][1], i2 = ridx[s][e][2];
            float add = rv[(0 * 64 + i0) * 96 + tp] + rv[(1 * 64 + i1) * 96 + tp] +
                        rv[(2 * 64 + i2) * 96 + tp];
            x += w * (vs[s][e][tp] + add);
        }
        if (active) xout[(size_t)p * 96 + tp] = x;  // xout aliases q: safe, own row only
    }
}

// ---------------------------------------------------------------- proj GEMM
// x (n,96) @ W_proj (96,96) + b -> out. W_proj staged in LDS once per block.
__global__ __launch_bounds__(192) void proj_kernel(
    const float* __restrict__ x, const float* __restrict__ W,
    const float* __restrict__ b, float* __restrict__ out, int n) {
    __shared__ float Wl[96 * 96];
    __shared__ float bl[96];
    __shared__ float xsh[2][96];
    const int t = threadIdx.x;
    for (int idx = t; idx < 96 * 96; idx += 192) Wl[idx] = W[idx];
    if (t < 96) bl[t] = b[t];
    const int rl = t / 96;
    const int o = t - rl * 96;
    for (int rbase = blockIdx.x * 2; rbase < n; rbase += gridDim.x * 2) {
        __syncthreads();
        {
            int r = rbase + rl;
            xsh[rl][o] = (r < n) ? x[(size_t)r * 96 + o] : 0.f;
        }
        __syncthreads();
        int r = rbase + rl;
        if (r < n) {
            float acc = bl[o];
#pragma unroll
            for (int d = 0; d < 96; d++) acc += xsh[rl][d] * Wl[d * 96 + o];
            out[(size_t)r * 96 + o] = acc;
        }
    }
}

// ---------------------------------------------------------------- launch
extern "C" void kernel_launch(void* const* d_in, const int* in_sizes, int n_in,
                              void* d_out, int out_size, void* d_ws, size_t ws_size,
                              hipStream_t stream) {
    const float* feats   = (const float*)d_in[0];
    const float* xyz     = (const float*)d_in[1];
    const int*   index_1 = (const int*)d_in[5];
    const float* shiftp  = (const float*)d_in[6];
    const float* W_qkv   = (const float*)d_in[7];
    const float* b_qkv   = (const float*)d_in[8];
    const float* table_q = (const float*)d_in[9];
    const float* table_k = (const float*)d_in[10];
    const float* table_v = (const float*)d_in[11];
    const float* W_proj  = (const float*)d_in[12];
    const float* b_proj  = (const float*)d_in[13];
    float* out = (float*)d_out;

    const int n = in_sizes[0] / NDIM;  // 50000

    float* w = (float*)d_ws;
    float* mn   = w;                       // 3 (pad 16)
    float* qbuf = w + 16;                  // n*96
    float* kbuf = qbuf + (size_t)n * 96;   // n*96
    float* vbuf = kbuf + (size_t)n * 96;   // n*96
    float* rq   = vbuf + (size_t)n * 96;   // 18432
    float* rk   = rq + 18432;
    float* rv   = rk + 18432;
    float* xbuf = qbuf;  // alias: q rows consumed only by their own block

    init_min_kernel<<<1, 64, 0, stream>>>(mn);
    min_reduce_kernel<<<256, 256, 0, stream>>>(xyz, n, mn);
    repack_kernel<<<(18432 + 255) / 256, 256, 0, stream>>>(table_q, table_k, table_v,
                                                           rq, rk, rv);
    qkv_kernel<<<dim3(9, 128), 256, 0, stream>>>(feats, W_qkv, b_qkv, qbuf, kbuf,
                                                 vbuf, n);
    attn_kernel<<<(n + 1) / 2, 192, 0, stream>>>(qbuf, kbuf, vbuf, xyz, index_1, rq,
                                                 rk, rv, mn, shiftp, xbuf, n);
    proj_kernel<<<2048, 192, 0, stream>>>(xbuf, W_proj, b_proj, out, n);
}

// Round 2
// 481.783 us; speedup vs baseline: 1.2742x; 1.2742x over previous
//
#include <hip/hip_runtime.h>
#include <math.h>

#define FLT_BIG 3.402823466e38f

// ---------------------------------------------------------------- min(xyz)
__global__ void init_min_kernel(float* mn) {
    if (threadIdx.x < 3) mn[threadIdx.x] = FLT_BIG;
}

__global__ void min_reduce_kernel(const float* __restrict__ xyz, int n, float* mn) {
    float m0 = FLT_BIG, m1 = FLT_BIG, m2 = FLT_BIG;
    for (int i = blockIdx.x * blockDim.x + threadIdx.x; i < n; i += gridDim.x * blockDim.x) {
        m0 = fminf(m0, xyz[3 * i + 0]);
        m1 = fminf(m1, xyz[3 * i + 1]);
        m2 = fminf(m2, xyz[3 * i + 2]);
    }
#pragma unroll
    for (int off = 32; off > 0; off >>= 1) {
        m0 = fminf(m0, __shfl_down(m0, off));
        m1 = fminf(m1, __shfl_down(m1, off));
        m2 = fminf(m2, __shfl_down(m2, off));
    }
    if ((threadIdx.x & 63) == 0) {
        // xyz >= 0 so float bits are monotone under signed int compare
        atomicMin((int*)&mn[0], __float_as_int(m0));
        atomicMin((int*)&mn[1], __float_as_int(m1));
        atomicMin((int*)&mn[2], __float_as_int(m2));
    }
}

// ---------------------------------------------------------------- table repack
// src layout [idx][h*16+d][c] (stride-3 in d) -> dst [c][idx][h*16+d] contiguous
__global__ void repack_kernel(const float* __restrict__ tq,
                              const float* __restrict__ tk,
                              const float* __restrict__ tv,
                              float* __restrict__ rq, float* __restrict__ rk,
                              float* __restrict__ rv) {
    int i = blockIdx.x * 256 + threadIdx.x;  // over 3*64*96 = 18432
    if (i < 3 * 64 * 96) {
        int c = i / (64 * 96);
        int rem = i - c * 64 * 96;
        int idx = rem / 96;
        int hd = rem - idx * 96;
        int src = (idx * 96 + hd) * 3 + c;
        rq[i] = tq[src];
        rk[i] = tk[src];
        rv[i] = tv[src];
    }
}

// ---------------------------------------------------------------- GEMM (n,96)@(96,96chunk)
// grid (nchunks, ceil(n/64)), block 192. Thread tile: 8 rows x 4 cols, all LDS
// traffic via ds_read_b128 (12 b128 per 128 FMAs).
__global__ __launch_bounds__(192) void gemm96_kernel(
    const float* __restrict__ X, const float* __restrict__ W, int wstride,
    const float* __restrict__ bias, float* __restrict__ out0,
    float* __restrict__ out1, float* __restrict__ out2, float scale0, int n) {
    __shared__ float Wl[96 * 96];
    __shared__ float4 xs[64][24];  // 64 rows x 96 floats

    const int t = threadIdx.x;
    const int c = blockIdx.x;
    float* outp = (c == 0) ? out0 : (c == 1 ? out1 : out2);
    const float scale = (c == 0) ? scale0 : 1.0f;

    for (int idx = t; idx < 9216; idx += 192) {
        int d = idx / 96, o = idx - d * 96;
        Wl[idx] = W[d * wstride + c * 96 + o];
    }

    const int os = t % 24;       // float4 col slot: cols 4*os..4*os+3
    const int rg = t / 24;       // 0..7 row group (8 rows each)
    const int o4 = os * 4;
    float4 bv;
    bv.x = bias[c * 96 + o4 + 0];
    bv.y = bias[c * 96 + o4 + 1];
    bv.z = bias[c * 96 + o4 + 2];
    bv.w = bias[c * 96 + o4 + 3];

    const int rbase = blockIdx.y * 64;
    // stage 64 rows of X (contiguous 6144 floats)
    const float4* X4 = (const float4*)X;
    for (int i = t; i < 1536; i += 192) {
        int gidx = rbase * 24 + i;
        float4 val = make_float4(0.f, 0.f, 0.f, 0.f);
        if (gidx < n * 24) val = X4[gidx];
        xs[i / 24][i % 24] = val;
    }
    __syncthreads();

    float4 acc[8];
#pragma unroll
    for (int r = 0; r < 8; r++) acc[r] = bv;

    for (int dc = 0; dc < 96; dc += 4) {
        float4 w0 = *(const float4*)&Wl[(dc + 0) * 96 + o4];
        float4 w1 = *(const float4*)&Wl[(dc + 1) * 96 + o4];
        float4 w2 = *(const float4*)&Wl[(dc + 2) * 96 + o4];
        float4 w3 = *(const float4*)&Wl[(dc + 3) * 96 + o4];
#pragma unroll
        for (int r = 0; r < 8; r++) {
            float4 xv = xs[rg * 8 + r][dc >> 2];
            acc[r].x += xv.x * w0.x + xv.y * w1.x + xv.z * w2.x + xv.w * w3.x;
            acc[r].y += xv.x * w0.y + xv.y * w1.y + xv.z * w2.y + xv.w * w3.y;
            acc[r].z += xv.x * w0.z + xv.y * w1.z + xv.z * w2.z + xv.w * w3.z;
            acc[r].w += xv.x * w0.w + xv.y * w1.w + xv.z * w2.w + xv.w * w3.w;
        }
    }

    float4* O4 = (float4*)outp;
#pragma unroll
    for (int r = 0; r < 8; r++) {
        int row = rbase + rg * 8 + r;
        if (row < n) {
            float4 v = acc[r];
            v.x *= scale; v.y *= scale; v.z *= scale; v.w *= scale;
            O4[row * 24 + os] = v;
        }
    }
}

// ---------------------------------------------------------------- fused attention
// block = 192 threads = 2 points (96 threads each). Exactly 16 edges/point.
// V stays in registers (loader thread == consumer thread); K staged in LDS
// with rows padded to 100 floats (float4-aligned, conflict-light).
__global__ __launch_bounds__(192) void attn_kernel(
    const float* q, const float* __restrict__ k, const float* __restrict__ v,
    const float* __restrict__ xyz, const int* __restrict__ index_1,
    const float* __restrict__ rq, const float* __restrict__ rk,
    const float* __restrict__ rv, const float* __restrict__ mn,
    const float* __restrict__ shiftp, float* xout, int n) {
    __shared__ float qs[2][96];
    __shared__ float ks[2][16][100];
    __shared__ float smw[2][6][16];
    __shared__ int je[2][16];
    __shared__ int ridx[2][16][3];

    const int s = threadIdx.x / 96;
    const int tp = threadIdx.x - s * 96;
    const int p = blockIdx.x * 2 + s;
    const bool active = p < n;

    const float shift = shiftp[0];

    // ---- rel quantized index: 48 threads/point, one per (e,c)
    if (active && tp < 48) {
        const int e = tp & 15;
        const int c = tp >> 4;
        const int jdx = index_1[(size_t)p * 16 + e];
        if (c == 0) je[s][e] = jdx;
        const float mnc = mn[c];
        float xi = floorf(fmodf(xyz[3 * p + c] - mnc + shift, 4.0f) * 4.0f);
        float xj = floorf(fmodf(xyz[3 * jdx + c] - mnc + shift, 4.0f) * 4.0f);
        ridx[s][e][c] = (int)(xi - xj) + 15;
    }
    __syncthreads();

    // ---- gather: q + k into LDS, v into registers
    float vreg[16];
    if (active) {
        qs[s][tp] = q[(size_t)p * 96 + tp];
#pragma unroll
        for (int e = 0; e < 16; e++) {
            int jdx = je[s][e];
            ks[s][e][tp] = k[(size_t)jdx * 96 + tp];
            vreg[e] = v[(size_t)jdx * 96 + tp];
        }
    }
    __syncthreads();

    // ---- scores + shuffle softmax: thread (h,e)
    const int h = tp >> 4;
    {
        const int e = tp & 15;
        const float4* q4 = (const float4*)&qs[s][h * 16];
        const float4* k4 = (const float4*)&ks[s][e][h * 16];
        float4 qa = q4[0], qb = q4[1], qc = q4[2], qd = q4[3];
        float4 ka = k4[0], kb = k4[1], kc = k4[2], kd = k4[3];
        float a = qa.x * ka.x + qa.y * ka.y + qa.z * ka.z + qa.w * ka.w +
                  qb.x * kb.x + qb.y * kb.y + qb.z * kb.z + qb.w * kb.w +
                  qc.x * kc.x + qc.y * kc.y + qc.z * kc.z + qc.w * kc.w +
                  qd.x * kd.x + qd.y * kd.y + qd.z * kd.z + qd.w * kd.w;
#pragma unroll
        for (int c = 0; c < 3; c++) {
            int idx = ridx[s][e][c];
            const float4* tq4 = (const float4*)(rq + ((c * 64 + idx) * 96 + h * 16));
            const float4* tk4 = (const float4*)(rk + ((c * 64 + idx) * 96 + h * 16));
            float4 ta = tq4[0], tb = tq4[1], tc = tq4[2], td = tq4[3];
            a += qa.x * ta.x + qa.y * ta.y + qa.z * ta.z + qa.w * ta.w +
                 qb.x * tb.x + qb.y * tb.y + qb.z * tb.z + qb.w * tb.w +
                 qc.x * tc.x + qc.y * tc.y + qc.z * tc.z + qc.w * tc.w +
                 qd.x * td.x + qd.y * td.y + qd.z * td.z + qd.w * td.w;
            float4 ua = tk4[0], ub = tk4[1], uc = tk4[2], ud = tk4[3];
            a += ka.x * ua.x + ka.y * ua.y + ka.z * ua.z + ka.w * ua.w +
                 kb.x * ub.x + kb.y * ub.y + kb.z * ub.z + kb.w * ub.w +
                 kc.x * uc.x + kc.y * uc.y + kc.z * uc.z + kc.w * uc.w +
                 kd.x * ud.x + kd.y * ud.y + kd.z * ud.z + kd.w * ud.w;
        }
        // width-16 softmax across e lanes (groups are 16-aligned in lane space)
        float m = a;
#pragma unroll
        for (int off = 8; off >= 1; off >>= 1) m = fmaxf(m, __shfl_xor(m, off, 16));
        float ex = __expf(a - m);
        float sum = ex;
#pragma unroll
        for (int off = 8; off >= 1; off >>= 1) sum += __shfl_xor(sum, off, 16);
        if (active) smw[s][h][e] = ex / sum;
    }
    __syncthreads();

    // ---- output: thread owns (h,d)=tp
    {
        float x = 0.f;
#pragma unroll
        for (int e = 0; e < 16; e++) {
            float wgt = smw[s][h][e];
            int i0 = ridx[s][e][0], i1 = ridx[s][e][1], i2 = ridx[s][e][2];
            float add = rv[i0 * 96 + tp] + rv[(64 + i1) * 96 + tp] +
                        rv[(128 + i2) * 96 + tp];
            x += wgt * (vreg[e] + add);
        }
        if (active) xout[(size_t)p * 96 + tp] = x;  // xout aliases q: own row only
    }
}

// ---------------------------------------------------------------- launch
extern "C" void kernel_launch(void* const* d_in, const int* in_sizes, int n_in,
                              void* d_out, int out_size, void* d_ws, size_t ws_size,
                              hipStream_t stream) {
    const float* feats   = (const float*)d_in[0];
    const float* xyz     = (const float*)d_in[1];
    const int*   index_1 = (const int*)d_in[5];
    const float* shiftp  = (const float*)d_in[6];
    const float* W_qkv   = (const float*)d_in[7];
    const float* b_qkv   = (const float*)d_in[8];
    const float* table_q = (const float*)d_in[9];
    const float* table_k = (const float*)d_in[10];
    const float* table_v = (const float*)d_in[11];
    const float* W_proj  = (const float*)d_in[12];
    const float* b_proj  = (const float*)d_in[13];
    float* out = (float*)d_out;

    const int n = in_sizes[0] / 96;  // 50000

    float* w = (float*)d_ws;
    float* mn   = w;                       // 3 (pad 16)
    float* qbuf = w + 16;                  // n*96
    float* kbuf = qbuf + (size_t)n * 96;   // n*96
    float* vbuf = kbuf + (size_t)n * 96;   // n*96
    float* rq   = vbuf + (size_t)n * 96;   // 18432
    float* rk   = rq + 18432;
    float* rv   = rk + 18432;
    float* xbuf = qbuf;  // alias: q rows consumed only by their own block

    const int GY = (n + 63) / 64;

    init_min_kernel<<<1, 64, 0, stream>>>(mn);
    min_reduce_kernel<<<256, 256, 0, stream>>>(xyz, n, mn);
    repack_kernel<<<(18432 + 255) / 256, 256, 0, stream>>>(table_q, table_k, table_v,
                                                           rq, rk, rv);
    gemm96_kernel<<<dim3(3, GY), 192, 0, stream>>>(feats, W_qkv, 288, b_qkv, qbuf,
                                                   kbuf, vbuf, 0.25f, n);
    attn_kernel<<<(n + 1) / 2, 192, 0, stream>>>(qbuf, kbuf, vbuf, xyz, index_1, rq,
                                                 rk, rv, mn, shiftp, xbuf, n);
    gemm96_kernel<<<dim3(1, GY), 192, 0, stream>>>(xbuf, W_proj, 96, b_proj, out,
                                                   out, out, 1.0f, n);
}